// Round 6
// baseline (232.642 us; speedup 1.0000x reference)
//
#include <hip/hip_runtime.h>
#include <hip/hip_bf16.h>

#define B_ 8
#define T_ 2048
#define NROWS 16384

typedef __attribute__((ext_vector_type(16))) float f32x16;
typedef __attribute__((ext_vector_type(8))) short short8;
typedef __fp16 half2_t __attribute__((ext_vector_type(2)));

__device__ __forceinline__ unsigned int pkrtz(float a, float b) {
    half2_t h = __builtin_amdgcn_cvt_pkrtz(a, b);
    return __builtin_bit_cast(unsigned int, h);
}
// pack two fp32 into one dword of bf16 (truncate): low short = a, high = b
__device__ __forceinline__ unsigned int pkbf(float a, float b) {
    return __builtin_amdgcn_perm(__float_as_uint(b), __float_as_uint(a), 0x07060302u);
}
__device__ __forceinline__ float dot2(unsigned int a, unsigned int b, float c) {
    return __builtin_amdgcn_fdot2(__builtin_bit_cast(half2_t, a),
                                  __builtin_bit_cast(half2_t, b), c, false);
}
__device__ __forceinline__ float fast_exp2(float x) {
#if __has_builtin(__builtin_amdgcn_exp2f)
    return __builtin_amdgcn_exp2f(x);
#else
    return exp2f(x);
#endif
}

// device-scope grid barrier; all 512 blocks are co-resident (2/CU by LDS).
__device__ __forceinline__ void grid_barrier(unsigned int* cnt, unsigned int target) {
    __syncthreads();
    if (threadIdx.x == 0) {
        __threadfence();                       // release: L2 writeback, device scope
        atomicAdd(cnt, 1u);
        while (__hip_atomic_load(cnt, __ATOMIC_RELAXED, __HIP_MEMORY_SCOPE_AGENT) < target)
            __builtin_amdgcn_s_sleep(2);
        __threadfence();                       // acquire: invalidate stale lines
    }
    __syncthreads();
}

// ---------------------------------------------------------------------------
// One persistent kernel, 512 blocks x 512 threads (exactly 2 blocks/CU by
// LDS), 3 phases separated by atomic grid barriers -> 1 dispatch instead of 3
// (each extra dependent dispatch measured ~20-25 us of drain/flush overhead).
// ---------------------------------------------------------------------------
__global__ __launch_bounds__(512, 4) void fused_kernel(
    const float* __restrict__ x,
    const float* __restrict__ Wq, const float* __restrict__ bq,
    const float* __restrict__ Wk, const float* __restrict__ bk,
    const float* __restrict__ Wv, const float* __restrict__ bv,
    const float* __restrict__ Wo, const float* __restrict__ bo,
    const float* __restrict__ tha, const float* __restrict__ thf,
    const float* __restrict__ W1, const float* __restrict__ b1,
    const float* __restrict__ W2, const float* __restrict__ b2,
    const float* __restrict__ g1, const float* __restrict__ be1,
    const float* __restrict__ g2, const float* __restrict__ be2,
    unsigned short* __restrict__ qb, unsigned short* __restrict__ kbuf,
    unsigned short* __restrict__ vbuf,
    float* __restrict__ attnbuf, float* __restrict__ outp,
    unsigned int* cnt)
{
    __shared__ unsigned int smem[15808];       // 63232 B, phase-aliased
    const int tid = threadIdx.x;
    const int lane = tid & 63;
    const int bid = blockIdx.x;

    // =====================================================================
    // Phase 1: QKV projection (dot2) + cos(.+theta) + bf16 pack. 32 rows/blk.
    // =====================================================================
    {
        unsigned int* xpk = smem;              // [32 kp][34]
        unsigned int* wpk = smem + 1088;       // [32 kp][196]
        unsigned int* outs = smem + 7360;      // [24 bh][32 r][4 dw]
        const int n0 = bid * 32;
        {
            float4 v = ((const float4*)(x + (size_t)n0 * 64))[tid];
            int r = tid >> 4, k0 = (tid & 15) * 4;
            xpk[(k0 >> 1) * 34 + r] = pkrtz(v.x, v.y);
            xpk[((k0 >> 1) + 1) * 34 + r] = pkrtz(v.z, v.w);
        }
        const float* Wm[3] = {Wq, Wk, Wv};
        #pragma unroll
        for (int t = 0; t < 6; t++) {          // 3072 float4 = 3 x (64x64)
            int fi = tid + t * 512;
            int m = fi >> 10, j = (fi >> 4) & 63, k0 = (fi & 15) * 4;
            float4 v = ((const float4*)Wm[m])[fi & 1023];
            wpk[(k0 >> 1) * 196 + m * 64 + j] = pkrtz(v.x, v.y);
            wpk[((k0 >> 1) + 1) * 196 + m * 64 + j] = pkrtz(v.z, v.w);
        }
        __syncthreads();

        const int r = tid & 31;                // 1 row
        const int c0 = (tid >> 5) * 12;        // x 12 cols
        float acc[12] = {};
        #pragma unroll 8
        for (int kp = 0; kp < 32; kp++) {
            unsigned int a = xpk[kp * 34 + r];
            uint4 b0 = *(const uint4*)&wpk[kp * 196 + c0];
            uint4 b1v = *(const uint4*)&wpk[kp * 196 + c0 + 4];
            uint4 b2v = *(const uint4*)&wpk[kp * 196 + c0 + 8];
            unsigned int bb[12] = {b0.x, b0.y, b0.z, b0.w,
                                   b1v.x, b1v.y, b1v.z, b1v.w,
                                   b2v.x, b2v.y, b2v.z, b2v.w};
            #pragma unroll
            for (int j = 0; j < 12; j++) acc[j] = dot2(a, bb[j], acc[j]);
        }
        {
            const float th = *tha;
            const float QS = 0.51006980f;      // log2(e)/sqrt(8)
            const float* biasp[3] = {bq, bk, bv};
            float vals[12];
            #pragma unroll
            for (int j = 0; j < 12; j++) {
                int c = c0 + j;
                float v = __cosf(acc[j] + biasp[c >> 6][c & 63] + th);
                vals[j] = (c >> 6) == 0 ? v * QS : v;
            }
            #pragma unroll
            for (int t = 0; t < 6; t++) {
                int c = c0 + 2 * t;
                outs[(c >> 3) * 128 + r * 4 + ((c & 7) >> 1)] = pkbf(vals[2*t], vals[2*t+1]);
            }
        }
        __syncthreads();
        unsigned short* outp3[3] = {qb, kbuf, vbuf};
        #pragma unroll
        for (int t = 0; t < 2; t++) {          // 768 uint4 coalesced stores
            int fi = tid + t * 512;
            if (fi < 768) {
                int bh = fi >> 5, r2 = fi & 31;
                int m = bh >> 3, hI = bh & 7;
                uint4 v = *(const uint4*)&outs[4 * fi];
                int n = n0 + r2;
                *(uint4*)(outp3[m] +
                    ((size_t)((n >> 11) * 8 + hI) * 2048 + (n & 2047)) * 8) = v;
            }
        }
    }
    grid_barrier(cnt, 512);

    // =====================================================================
    // Phase 2: flash attention, S^T form, 32x32x16 bf16 MFMA. 8 waves x 32q.
    // lsum comes FREE from a ones-row (d=8) in V^T via oacc[4]. V^T stored
    // with bit2<->bit3 s-swizzle so the PV A-frag is one b128.
    // =====================================================================
    {
        unsigned short* Ks = (unsigned short*)smem;          // [1024][8]
        unsigned short* Vt = (unsigned short*)(smem + 4096); // [9][1032]
        const int head = bid >> 3;             // b*8 + h
        const int qseg = bid & 7;
        const size_t hoff = (size_t)head * T_ * 8;
        const int wave = tid >> 6;
        const int col = lane & 31, h = lane >> 5;
        const int q0 = qseg * 256 + wave * 32;

        const short8 z8 = {0, 0, 0, 0, 0, 0, 0, 0};
        short8 bqf = z8;                       // Q B-frag: n=q, k=d
        if (h == 0) bqf = *(const short8*)(qb + hoff + (size_t)(q0 + col) * 8);

        // ones row (d=8) of V^T: Sum_s p = oacc row 8
        if (tid < 128)
            ((uint4*)(Vt + 8 * 1032))[tid] =
                make_uint4(0x3f803f80u, 0x3f803f80u, 0x3f803f80u, 0x3f803f80u);

        f32x16 oacc = {0.f,0.f,0.f,0.f,0.f,0.f,0.f,0.f,0.f,0.f,0.f,0.f,0.f,0.f,0.f,0.f};
        const f32x16 z16 = {0.f,0.f,0.f,0.f,0.f,0.f,0.f,0.f,0.f,0.f,0.f,0.f,0.f,0.f,0.f,0.f};

        for (int half = 0; half < 2; half++) {
            __syncthreads();
            {
                const uint4* kg = (const uint4*)(kbuf + hoff + (size_t)half * 1024 * 8);
                const uint4* vg = (const uint4*)(vbuf + hoff + (size_t)half * 1024 * 8);
                #pragma unroll
                for (int it = 0; it < 2; it++) {
                    int s = tid + it * 512;
                    ((uint4*)Ks)[s] = kg[s];
                    union { uint4 u; unsigned short us[8]; } cv;
                    cv.u = vg[s];
                    int sp = (s & ~12) | ((s & 4) << 1) | ((s & 8) >> 1);  // pi swizzle
                    #pragma unroll
                    for (int d = 0; d < 8; d++) Vt[d * 1032 + sp] = cv.us[d];
                }
            }
            __syncthreads();

            for (int s0 = 0; s0 < 1024; s0 += 32) {
                short8 ak = z8;                // K A-frag: m=key, k=d
                if (h == 0) ak = *(const short8*)&Ks[(s0 + col) * 8];
                f32x16 S = __builtin_amdgcn_mfma_f32_32x32x16_bf16(ak, bqf, z16, 0, 0, 0);
                #pragma unroll
                for (int g = 0; g < 2; g++) {  // keys [s0+16g, s0+16g+16)
                    const int o = g * 8;
                    union { unsigned int u[4]; short8 s; } bp;
                    bp.u[0] = pkbf(fast_exp2(S[o+0]), fast_exp2(S[o+1]));
                    bp.u[1] = pkbf(fast_exp2(S[o+2]), fast_exp2(S[o+3]));
                    bp.u[2] = pkbf(fast_exp2(S[o+4]), fast_exp2(S[o+5]));
                    bp.u[3] = pkbf(fast_exp2(S[o+6]), fast_exp2(S[o+7]));
                    short8 av = z8;            // V^T A-frag (pi-contiguous b128)
                    if (col < 9)
                        av = *(const short8*)&Vt[col * 1032 + s0 + g * 16 + 8 * h];
                    oacc = __builtin_amdgcn_mfma_f32_32x32x16_bf16(av, bp.s, oacc, 0, 0, 0);
                }
            }
        }

        float tot = oacc[4];                   // C[8][q] on h=0 lanes, 0 on h=1
        tot += __shfl_xor(tot, 32);
        const float inv = 1.0f / tot;
        const int bI = head >> 3, hI = head & 7;
        const int q = q0 + col;
        #pragma unroll
        for (int rr = 0; rr < 4; rr++) {       // O^T regs 0-3: d = 4h + rr
            int d = 4 * h + rr;
            attnbuf[((size_t)bI * 2048 + q) * 64 + hI * 8 + d] = oacc[rr] * inv;
        }
    }
    grid_barrier(cnt, 1024);

    // =====================================================================
    // Phase 3: tail. y=At@Wo^T+bo; x1=LN(x+y); qout=cos(x1)cos(thf);
    // h=relu(qout@W1^T+b1); f=h@W2^T+b2; out=LN(x1+f). 32 rows/block.
    // =====================================================================
    {
        unsigned int* Wbuf = smem;             // Wo [32][68]; W2p reuses
        unsigned int* qpk  = smem + 10496;     // [32 kp][34]
        unsigned int* Upk  = smem + 11584;     // At [32][34] then hrow [32][132]
        unsigned int* const W1p = Wbuf + 2176; // [32 kp][260]
        unsigned int* const W2p = Wbuf;        // [128 fp][68]
        unsigned int* const hrow = Upk;
        const int n0 = bid * 32;

        const int rp = ((tid >> 6) & 3) * 4 + (lane & 3);
        const int r0 = rp * 2;
        const int c0 = ((lane >> 2) & 15) * 4;

        float4 atv = ((const float4*)(attnbuf + (size_t)n0 * 64))[tid];
        float4 wo0 = ((const float4*)Wo)[tid];
        float4 wo1 = ((const float4*)Wo)[tid + 512];
        float4 xv0 = *(const float4*)(x + (size_t)(n0 + r0) * 64 + c0);
        float4 xv1 = *(const float4*)(x + (size_t)(n0 + r0 + 1) * 64 + c0);
        float4 w1r[8];
        #pragma unroll
        for (int t = 0; t < 8; t++) w1r[t] = ((const float4*)W1)[tid + t * 512];

        {
            int r = tid >> 4, k0 = (tid & 15) * 4;
            Upk[(k0 >> 1) * 34 + r] = pkrtz(atv.x, atv.y);
            Upk[((k0 >> 1) + 1) * 34 + r] = pkrtz(atv.z, atv.w);
            Wbuf[(k0 >> 1) * 68 + r] = pkrtz(wo0.x, wo0.y);
            Wbuf[((k0 >> 1) + 1) * 68 + r] = pkrtz(wo0.z, wo0.w);
            int fi = tid + 512;
            int r2 = fi >> 4, k2 = (fi & 15) * 4;
            Wbuf[(k2 >> 1) * 68 + r2] = pkrtz(wo1.x, wo1.y);
            Wbuf[((k2 >> 1) + 1) * 68 + r2] = pkrtz(wo1.z, wo1.w);
        }
        __syncthreads();

        #pragma unroll
        for (int t = 0; t < 8; t++) {          // W1 regs -> LDS
            int fi = tid + t * 512;
            int f = fi >> 4, k0 = (fi & 15) * 4;
            W1p[(k0 >> 1) * 260 + f] = pkrtz(w1r[t].x, w1r[t].y);
            W1p[((k0 >> 1) + 1) * 260 + f] = pkrtz(w1r[t].z, w1r[t].w);
        }

        float x1v[2][4];
        if (tid < 256) {                       // GEMM1 + ep1
            float acc1[2][4] = {};
            #pragma unroll 8
            for (int kp = 0; kp < 32; kp++) {
                uint2 a = *(const uint2*)&Upk[kp * 34 + r0];
                uint4 b = *(const uint4*)&Wbuf[kp * 68 + c0];
                unsigned int bb[4] = {b.x, b.y, b.z, b.w};
                #pragma unroll
                for (int j = 0; j < 4; j++) {
                    acc1[0][j] = dot2(a.x, bb[j], acc1[0][j]);
                    acc1[1][j] = dot2(a.y, bb[j], acc1[1][j]);
                }
            }
            float4 bo4 = *(const float4*)&bo[c0];
            float4 g14 = *(const float4*)&g1[c0];
            float4 be14 = *(const float4*)&be1[c0];
            float gg[4] = {g14.x, g14.y, g14.z, g14.w};
            float eb[4] = {be14.x, be14.y, be14.z, be14.w};
            float bb4[4] = {bo4.x, bo4.y, bo4.z, bo4.w};
            float cth = __cosf(*thf);
            #pragma unroll
            for (int i = 0; i < 2; i++) {
                float4 xv = i ? xv1 : xv0;
                float vv[4] = {xv.x + acc1[i][0] + bb4[0], xv.y + acc1[i][1] + bb4[1],
                               xv.z + acc1[i][2] + bb4[2], xv.w + acc1[i][3] + bb4[3]};
                float s1 = vv[0] + vv[1] + vv[2] + vv[3];
                float s2 = vv[0]*vv[0] + vv[1]*vv[1] + vv[2]*vv[2] + vv[3]*vv[3];
                #pragma unroll
                for (int m = 4; m <= 32; m <<= 1) {
                    s1 += __shfl_xor(s1, m);
                    s2 += __shfl_xor(s2, m);
                }
                float mean = s1 * 0.015625f;
                float rstd = rsqrtf(s2 * 0.015625f - mean * mean + 1e-5f);
                float qv[4];
                #pragma unroll
                for (int j = 0; j < 4; j++) {
                    x1v[i][j] = (vv[j] - mean) * rstd * gg[j] + eb[j];
                    qv[j] = __cosf(x1v[i][j]) * cth;
                }
                qpk[((c0 >> 1) + 0) * 34 + r0 + i] = pkrtz(qv[0], qv[1]);
                qpk[((c0 >> 1) + 1) * 34 + r0 + i] = pkrtz(qv[2], qv[3]);
            }
        }
        __syncthreads();

        float4 w2r[8];
        #pragma unroll
        for (int t = 0; t < 8; t++) w2r[t] = ((const float4*)W2)[tid + t * 512];

        {                                      // GEMM2: all 512 threads
            const int r2 = (tid & 15) * 2;
            const int f0 = (tid >> 4) * 8;
            float acc2[2][8] = {};
            #pragma unroll 4
            for (int kp = 0; kp < 32; kp++) {
                uint2 a = *(const uint2*)&qpk[kp * 34 + r2];
                uint4 b0 = *(const uint4*)&W1p[kp * 260 + f0];
                uint4 b1q = *(const uint4*)&W1p[kp * 260 + f0 + 4];
                unsigned int bb[8] = {b0.x, b0.y, b0.z, b0.w, b1q.x, b1q.y, b1q.z, b1q.w};
                #pragma unroll
                for (int j = 0; j < 8; j++) {
                    acc2[0][j] = dot2(a.x, bb[j], acc2[0][j]);
                    acc2[1][j] = dot2(a.y, bb[j], acc2[1][j]);
                }
            }
            float4 c1a = *(const float4*)&b1[f0];
            float4 c1b = *(const float4*)&b1[f0 + 4];
            float bb[8] = {c1a.x, c1a.y, c1a.z, c1a.w, c1b.x, c1b.y, c1b.z, c1b.w};
            __syncthreads();                   // qpk/W1p reads done before hrow/W2p writes
            #pragma unroll
            for (int i = 0; i < 2; i++) {
                float hv[8];
                #pragma unroll
                for (int j = 0; j < 8; j++) hv[j] = fmaxf(acc2[i][j] + bb[j], 0.f);
                uint4 hq;
                hq.x = pkrtz(hv[0], hv[1]); hq.y = pkrtz(hv[2], hv[3]);
                hq.z = pkrtz(hv[4], hv[5]); hq.w = pkrtz(hv[6], hv[7]);
                *(uint4*)&hrow[(r2 + i) * 132 + (f0 >> 1)] = hq;
            }
        }

        #pragma unroll
        for (int t = 0; t < 8; t++) {          // W2 regs -> LDS
            int fi = tid + t * 512;
            int e = fi >> 6, k0 = (fi & 63) * 4;
            W2p[(k0 >> 1) * 68 + e] = pkrtz(w2r[t].x, w2r[t].y);
            W2p[((k0 >> 1) + 1) * 68 + e] = pkrtz(w2r[t].z, w2r[t].w);
        }
        __syncthreads();

        if (tid < 256) {                       // GEMM3 + ep3
            float acc3[2][4] = {};
            #pragma unroll 4
            for (int fp0 = 0; fp0 < 128; fp0 += 4) {
                uint4 a0 = *(const uint4*)&hrow[(r0 + 0) * 132 + fp0];
                uint4 a1 = *(const uint4*)&hrow[(r0 + 1) * 132 + fp0];
                uint4 b0 = *(const uint4*)&W2p[(fp0 + 0) * 68 + c0];
                uint4 b1q = *(const uint4*)&W2p[(fp0 + 1) * 68 + c0];
                uint4 b2q = *(const uint4*)&W2p[(fp0 + 2) * 68 + c0];
                uint4 b3q = *(const uint4*)&W2p[(fp0 + 3) * 68 + c0];
                unsigned int aa[2][4] = {{a0.x, a0.y, a0.z, a0.w},
                                         {a1.x, a1.y, a1.z, a1.w}};
                unsigned int bbb[4][4] = {{b0.x, b0.y, b0.z, b0.w},
                                          {b1q.x, b1q.y, b1q.z, b1q.w},
                                          {b2q.x, b2q.y, b2q.z, b2q.w},
                                          {b3q.x, b3q.y, b3q.z, b3q.w}};
                #pragma unroll
                for (int i = 0; i < 2; i++)
                    #pragma unroll
                    for (int j = 0; j < 4; j++) {
                        float t0 = dot2(aa[i][0], bbb[0][j], acc3[i][j]);
                        t0 = dot2(aa[i][1], bbb[1][j], t0);
                        t0 = dot2(aa[i][2], bbb[2][j], t0);
                        acc3[i][j] = dot2(aa[i][3], bbb[3][j], t0);
                    }
            }
            float4 b24 = *(const float4*)&b2[c0];
            float4 g24 = *(const float4*)&g2[c0];
            float4 be24 = *(const float4*)&be2[c0];
            #pragma unroll
            for (int i = 0; i < 2; i++) {
                float vv[4] = {x1v[i][0] + acc3[i][0] + b24.x,
                               x1v[i][1] + acc3[i][1] + b24.y,
                               x1v[i][2] + acc3[i][2] + b24.z,
                               x1v[i][3] + acc3[i][3] + b24.w};
                float s1 = vv[0] + vv[1] + vv[2] + vv[3];
                float s2 = vv[0]*vv[0] + vv[1]*vv[1] + vv[2]*vv[2] + vv[3]*vv[3];
                #pragma unroll
                for (int m = 4; m <= 32; m <<= 1) {
                    s1 += __shfl_xor(s1, m);
                    s2 += __shfl_xor(s2, m);
                }
                float mean = s1 * 0.015625f;
                float rstd = rsqrtf(s2 * 0.015625f - mean * mean + 1e-5f);
                float4 o;
                o.x = (vv[0] - mean) * rstd * g24.x + be24.x;
                o.y = (vv[1] - mean) * rstd * g24.y + be24.y;
                o.z = (vv[2] - mean) * rstd * g24.z + be24.z;
                o.w = (vv[3] - mean) * rstd * g24.w + be24.w;
                *(float4*)(outp + (size_t)(n0 + r0 + i) * 64 + c0) = o;
            }
        }
    }
}

// ---------------------------------------------------------------------------
extern "C" void kernel_launch(void* const* d_in, const int* in_sizes, int n_in,
                              void* d_out, int out_size, void* d_ws, size_t ws_size,
                              hipStream_t stream)
{
    const float* x   = (const float*)d_in[0];
    const float* Wq  = (const float*)d_in[1];
    const float* bq  = (const float*)d_in[2];
    const float* Wk  = (const float*)d_in[3];
    const float* bk  = (const float*)d_in[4];
    const float* Wv  = (const float*)d_in[5];
    const float* bv  = (const float*)d_in[6];
    const float* Wo  = (const float*)d_in[7];
    const float* bo  = (const float*)d_in[8];
    const float* tha = (const float*)d_in[9];
    const float* thf = (const float*)d_in[10];
    const float* W1  = (const float*)d_in[11];
    const float* b1  = (const float*)d_in[12];
    const float* W2  = (const float*)d_in[13];
    const float* b2  = (const float*)d_in[14];
    const float* g1  = (const float*)d_in[15];
    const float* be1 = (const float*)d_in[16];
    const float* g2  = (const float*)d_in[17];
    const float* be2 = (const float*)d_in[18];

    // workspace: qb(2M) kb(2M) vb(2M) attn(4M) | counter at 10M
    char* wsb = (char*)d_ws;
    unsigned short* qbp = (unsigned short*)(wsb);
    unsigned short* kbp = (unsigned short*)(wsb + (2u << 20));
    unsigned short* vbp = (unsigned short*)(wsb + (4u << 20));
    float* attnb = (float*)(wsb + (6u << 20));
    unsigned int* cnt = (unsigned int*)(wsb + (10u << 20));

    hipMemsetAsync(cnt, 0, 64, stream);
    fused_kernel<<<512, 512, 0, stream>>>(
        x, Wq, bq, Wk, bk, Wv, bv, Wo, bo, tha, thf,
        W1, b1, W2, b2, g1, be1, g2, be2,
        qbp, kbp, vbp, attnb, (float*)d_out, cnt);
}

// Round 7
// 148.721 us; speedup vs baseline: 1.5643x; 1.5643x over previous
//
#include <hip/hip_runtime.h>
#include <hip/hip_bf16.h>

#define B_ 8
#define T_ 2048
#define NROWS 16384

typedef __attribute__((ext_vector_type(16))) float f32x16;
typedef __attribute__((ext_vector_type(8))) short short8;
typedef __fp16 half2_t __attribute__((ext_vector_type(2)));

__device__ __forceinline__ unsigned int pkrtz(float a, float b) {
    half2_t h = __builtin_amdgcn_cvt_pkrtz(a, b);
    return __builtin_bit_cast(unsigned int, h);
}
// pack two fp32 into one dword of bf16 (truncate): low short = a, high = b
__device__ __forceinline__ unsigned int pkbf(float a, float b) {
    return __builtin_amdgcn_perm(__float_as_uint(b), __float_as_uint(a), 0x07060302u);
}
__device__ __forceinline__ float dot2(unsigned int a, unsigned int b, float c) {
    return __builtin_amdgcn_fdot2(__builtin_bit_cast(half2_t, a),
                                  __builtin_bit_cast(half2_t, b), c, false);
}
__device__ __forceinline__ float fast_exp2(float x) {
#if __has_builtin(__builtin_amdgcn_exp2f)
    return __builtin_amdgcn_exp2f(x);
#else
    return exp2f(x);
#endif
}

// ---------------------------------------------------------------------------
// Kernel 1: QKV projection (dot2) + cos(.+theta) + bf16 pack to [B,H,T,DK].
// 64 rows/block, 2 rows x 12 cols per thread. Output through flat LDS tile ->
// coalesced uint4 stores. q scaled by log2(e)/sqrt(8).
// ---------------------------------------------------------------------------
__global__ __launch_bounds__(512, 2) void qkv_kernel(
    const float* __restrict__ x,
    const float* __restrict__ Wq, const float* __restrict__ bq,
    const float* __restrict__ Wk, const float* __restrict__ bk,
    const float* __restrict__ Wv, const float* __restrict__ bv,
    const float* __restrict__ theta_attn,
    unsigned short* __restrict__ qb, unsigned short* __restrict__ kbuf,
    unsigned short* __restrict__ vbuf)
{
    __shared__ unsigned int xpk[32 * 66];     // fp16 pairs of x^T: [kpair][row0..63]
    __shared__ unsigned int wpk[32 * 196];    // fp16 pairs of W^T: [kpair][col0..191]
    __shared__ unsigned int outs[6144];       // bf16 out: [(c>>3)][row][4 dwords] linear
    const int tid = threadIdx.x;
    const int n0 = blockIdx.x * 64;

    #pragma unroll
    for (int t = 0; t < 2; t++) {             // 1024 float4 = 64x64 x
        int fi = tid + t * 512;
        float4 v = ((const float4*)(x + (size_t)n0 * 64))[fi];
        int r = fi >> 4, k0 = (fi & 15) * 4;
        xpk[(k0 >> 1) * 66 + r] = pkrtz(v.x, v.y);
        xpk[((k0 >> 1) + 1) * 66 + r] = pkrtz(v.z, v.w);
    }
    const float* Wm[3] = {Wq, Wk, Wv};
    #pragma unroll
    for (int t = 0; t < 6; t++) {             // 3072 float4 = 3 x (64x64)
        int fi = tid + t * 512;
        int m = fi >> 10, j = (fi >> 4) & 63, k0 = (fi & 15) * 4;
        float4 v = ((const float4*)Wm[m])[fi & 1023];
        wpk[(k0 >> 1) * 196 + m * 64 + j] = pkrtz(v.x, v.y);
        wpk[((k0 >> 1) + 1) * 196 + m * 64 + j] = pkrtz(v.z, v.w);
    }
    __syncthreads();

    const int r0 = (tid & 31) * 2;            // 2 rows
    const int c0 = (tid >> 5) * 12;           // x 12 cols
    float acc[2][12] = {};
    #pragma unroll 8
    for (int kp = 0; kp < 32; kp++) {
        uint2 a = *(const uint2*)&xpk[kp * 66 + r0];
        uint4 b0 = *(const uint4*)&wpk[kp * 196 + c0];
        uint4 b1 = *(const uint4*)&wpk[kp * 196 + c0 + 4];
        uint4 b2 = *(const uint4*)&wpk[kp * 196 + c0 + 8];
        unsigned int bb[12] = {b0.x, b0.y, b0.z, b0.w,
                               b1.x, b1.y, b1.z, b1.w,
                               b2.x, b2.y, b2.z, b2.w};
        #pragma unroll
        for (int j = 0; j < 12; j++) {
            acc[0][j] = dot2(a.x, bb[j], acc[0][j]);
            acc[1][j] = dot2(a.y, bb[j], acc[1][j]);
        }
    }

    {
        const float th = *theta_attn;
        const float QS = 0.51006980f;         // log2(e)/sqrt(8)
        const float* biasp[3] = {bq, bk, bv};
        float bcol[12];
        #pragma unroll
        for (int j = 0; j < 12; j++) {
            int c = c0 + j;
            bcol[j] = biasp[c >> 6][c & 63];
        }
        #pragma unroll
        for (int i = 0; i < 2; i++) {
            float vals[12];
            #pragma unroll
            for (int j = 0; j < 12; j++) {
                float v = __cosf(acc[i][j] + bcol[j] + th);
                vals[j] = ((c0 + j) >> 6) == 0 ? v * QS : v;
            }
            int row = r0 + i;
            #pragma unroll
            for (int t = 0; t < 6; t++) {
                int c = c0 + 2 * t;
                outs[(c >> 3) * 256 + row * 4 + ((c & 7) >> 1)] = pkbf(vals[2*t], vals[2*t+1]);
            }
        }
    }
    __syncthreads();

    unsigned short* outp3[3] = {qb, kbuf, vbuf};
    #pragma unroll
    for (int t = 0; t < 3; t++) {             // 1536 uint4 stores, linear LDS re-read
        int fi = tid + t * 512;
        int bh = fi >> 6, r2 = fi & 63;       // bh wave-uniform
        int m = bh >> 3, hI = bh & 7;
        uint4 v = *(const uint4*)&outs[4 * fi];
        int n = n0 + r2;
        unsigned short* dst = outp3[m] +
            ((size_t)((n >> 11) * 8 + hI) * 2048 + (n & 2047)) * 8;
        *(uint4*)dst = v;
    }
}

// ---------------------------------------------------------------------------
// Kernel 2: flash attention, S^T form, 32x32x16 bf16 MFMA.
// - lsum comes FREE from a ones-row (d=8) in V^T via oacc[4].
// - V^T staged with bit2<->bit3 s-swizzle so PV A-frag is ONE b128.
// - No per-chunk fragment re-zeroing: ak is loop-carried (masked load only
//   writes h=0 lanes), av is an UNCONDITIONAL read with hoisted min(col,8)
//   row clamp (garbage/dup rows only affect C rows 9-31, never read).
// No-max softmax exact: |s| <= 8/sqrt(8).
// ---------------------------------------------------------------------------
__global__ __launch_bounds__(256, 4) void attn_kernel(
    const unsigned short* __restrict__ qb,
    const unsigned short* __restrict__ kbuf,
    const unsigned short* __restrict__ vbuf,
    float* __restrict__ attn)
{
    __shared__ __align__(16) unsigned short Ks[1024 * 8];  // K rows bf16, half of T
    __shared__ __align__(16) unsigned short Vt[9 * 1032];  // V^T bf16 (+ones row 8)
    const int tid = threadIdx.x;
    const int head = blockIdx.x >> 4;         // b*8 + h
    const int qblk = blockIdx.x & 15;
    const size_t hoff = (size_t)head * T_ * 8;
    const int wave = tid >> 6, lane = tid & 63;
    const int col = lane & 31, h = lane >> 5;
    const int q0 = qblk * 128 + wave * 32;

    const short8 z8 = {0, 0, 0, 0, 0, 0, 0, 0};
    short8 bqf = z8;                          // Q B-frag: n=q, k=d (h=1 lanes stay 0)
    if (h == 0) bqf = *(const short8*)(qb + hoff + (size_t)(q0 + col) * 8);

    // ones row (d=8): its C row accumulates Sum_s p
    if (tid < 128)
        ((uint4*)(Vt + 8 * 1032))[tid] =
            make_uint4(0x3f803f80u, 0x3f803f80u, 0x3f803f80u, 0x3f803f80u);

    f32x16 oacc = {0.f,0.f,0.f,0.f,0.f,0.f,0.f,0.f,0.f,0.f,0.f,0.f,0.f,0.f,0.f,0.f};
    const f32x16 z16 = {0.f,0.f,0.f,0.f,0.f,0.f,0.f,0.f,0.f,0.f,0.f,0.f,0.f,0.f,0.f,0.f};
    const unsigned short* vbase = &Vt[(col < 9 ? col : 8) * 1032 + 8 * h];
    short8 ak = z8;                           // loop-carried; h=1 lanes stay 0

    for (int half = 0; half < 2; half++) {
        __syncthreads();
        {
            const uint4* kg = (const uint4*)(kbuf + hoff + (size_t)half * 1024 * 8);
            const uint4* vg = (const uint4*)(vbuf + hoff + (size_t)half * 1024 * 8);
            #pragma unroll
            for (int it = 0; it < 4; it++) {
                int s = tid + it * 256;
                ((uint4*)Ks)[s] = kg[s];
                union { uint4 u; unsigned short us[8]; } cv;
                cv.u = vg[s];
                int sp = (s & ~12) | ((s & 4) << 1) | ((s & 8) >> 1);  // pi swizzle
                #pragma unroll
                for (int d = 0; d < 8; d++) Vt[d * 1032 + sp] = cv.us[d];
            }
        }
        __syncthreads();

        for (int s0 = 0; s0 < 1024; s0 += 32) {
            if (h == 0) ak = *(const short8*)&Ks[(s0 + col) * 8];
            f32x16 S = __builtin_amdgcn_mfma_f32_32x32x16_bf16(ak, bqf, z16, 0, 0, 0);
            #pragma unroll
            for (int g = 0; g < 2; g++) {     // keys [s0+16g, s0+16g+16)
                const int o = g * 8;
                union { unsigned int u[4]; short8 s; } bp;
                bp.u[0] = pkbf(fast_exp2(S[o+0]), fast_exp2(S[o+1]));
                bp.u[1] = pkbf(fast_exp2(S[o+2]), fast_exp2(S[o+3]));
                bp.u[2] = pkbf(fast_exp2(S[o+4]), fast_exp2(S[o+5]));
                bp.u[3] = pkbf(fast_exp2(S[o+6]), fast_exp2(S[o+7]));
                short8 av = *(const short8*)&vbase[s0 + g * 16];  // unconditional b128
                oacc = __builtin_amdgcn_mfma_f32_32x32x16_bf16(av, bp.s, oacc, 0, 0, 0);
            }
        }
    }

    float tot = oacc[4];                      // C[8][q] on h=0 lanes, 0 on h=1
    tot += __shfl_xor(tot, 32);
    const float inv = 1.0f / tot;
    const int bI = head >> 3, hI = head & 7;
    const int q = q0 + col;
    #pragma unroll
    for (int rr = 0; rr < 4; rr++) {          // O^T regs 0-3: d = 4h + rr
        int d = 4 * h + rr;
        attn[((size_t)bI * 2048 + q) * 64 + hI * 8 + d] = oacc[rr] * inv;
    }
}

// ---------------------------------------------------------------------------
// Kernel 3 (fused tail): y=attn@Wo^T+bo; x1=LN(x+y); qout=cos(x1)cos(thf);
// h=relu(qout@W1^T+b1); f=h@W2^T+b2; out=LN(x1+f). 32 rows/block.
// ---------------------------------------------------------------------------
__global__ __launch_bounds__(512, 4) void tail_kernel(
    const float* __restrict__ attn, const float* __restrict__ x,
    const float* __restrict__ Wo, const float* __restrict__ bo,
    const float* __restrict__ g1, const float* __restrict__ be1,
    const float* __restrict__ theta_ffn,
    const float* __restrict__ W1, const float* __restrict__ b1,
    const float* __restrict__ W2, const float* __restrict__ b2,
    const float* __restrict__ g2, const float* __restrict__ be2,
    float* __restrict__ outp)
{
    __shared__ unsigned int Wbuf[10496];  // Wo [32][68] | W1p at +2176 [32][260]; W2p at +0 [128][68]
    __shared__ unsigned int qpk[32 * 34]; // qout fp16 pairs [kpair][row]
    __shared__ unsigned int Upk[32 * 132];// At pairs [32][34]; then hrow [32][132]
    const int tid = threadIdx.x;
    const int lane = tid & 63;
    const int n0 = blockIdx.x * 32;
    unsigned int* const W1p = Wbuf + 2176;
    unsigned int* const W2p = Wbuf;
    unsigned int* const hrow = Upk;

    const int rp = ((tid >> 6) & 3) * 4 + (lane & 3);   // 0..15 (waves 0-3)
    const int r0 = rp * 2;
    const int c0 = ((lane >> 2) & 15) * 4;

    float4 atv = ((const float4*)(attn + (size_t)n0 * 64))[tid];
    float4 wo0 = ((const float4*)Wo)[tid];
    float4 wo1 = ((const float4*)Wo)[tid + 512];
    float4 xv0 = *(const float4*)(x + (size_t)(n0 + r0) * 64 + c0);
    float4 xv1 = *(const float4*)(x + (size_t)(n0 + r0 + 1) * 64 + c0);
    float4 w1r[8];
    #pragma unroll
    for (int t = 0; t < 8; t++) w1r[t] = ((const float4*)W1)[tid + t * 512];

    {
        int r = tid >> 4, k0 = (tid & 15) * 4;
        Upk[(k0 >> 1) * 34 + r] = pkrtz(atv.x, atv.y);
        Upk[((k0 >> 1) + 1) * 34 + r] = pkrtz(atv.z, atv.w);
        Wbuf[(k0 >> 1) * 68 + r] = pkrtz(wo0.x, wo0.y);
        Wbuf[((k0 >> 1) + 1) * 68 + r] = pkrtz(wo0.z, wo0.w);
        int fi = tid + 512;
        int r2 = fi >> 4, k2 = (fi & 15) * 4;
        Wbuf[(k2 >> 1) * 68 + r2] = pkrtz(wo1.x, wo1.y);
        Wbuf[((k2 >> 1) + 1) * 68 + r2] = pkrtz(wo1.z, wo1.w);
    }
    __syncthreads();

    #pragma unroll
    for (int t = 0; t < 8; t++) {             // W1 regs -> LDS
        int fi = tid + t * 512;
        int f = fi >> 4, k0 = (fi & 15) * 4;
        W1p[(k0 >> 1) * 260 + f] = pkrtz(w1r[t].x, w1r[t].y);
        W1p[((k0 >> 1) + 1) * 260 + f] = pkrtz(w1r[t].z, w1r[t].w);
    }

    float x1v[2][4];
    if (tid < 256) {                          // GEMM1 + ep1
        float acc1[2][4] = {};
        #pragma unroll 8
        for (int kp = 0; kp < 32; kp++) {
            uint2 a = *(const uint2*)&Upk[kp * 34 + r0];
            uint4 b = *(const uint4*)&Wbuf[kp * 68 + c0];
            unsigned int bb[4] = {b.x, b.y, b.z, b.w};
            #pragma unroll
            for (int j = 0; j < 4; j++) {
                acc1[0][j] = dot2(a.x, bb[j], acc1[0][j]);
                acc1[1][j] = dot2(a.y, bb[j], acc1[1][j]);
            }
        }
        float4 bo4 = *(const float4*)&bo[c0];
        float4 g14 = *(const float4*)&g1[c0];
        float4 be14 = *(const float4*)&be1[c0];
        float gg[4] = {g14.x, g14.y, g14.z, g14.w};
        float eb[4] = {be14.x, be14.y, be14.z, be14.w};
        float bb4[4] = {bo4.x, bo4.y, bo4.z, bo4.w};
        float cth = __cosf(*theta_ffn);
        #pragma unroll
        for (int i = 0; i < 2; i++) {
            float4 xv = i ? xv1 : xv0;
            float vv[4] = {xv.x + acc1[i][0] + bb4[0], xv.y + acc1[i][1] + bb4[1],
                           xv.z + acc1[i][2] + bb4[2], xv.w + acc1[i][3] + bb4[3]};
            float s1 = vv[0] + vv[1] + vv[2] + vv[3];
            float s2 = vv[0]*vv[0] + vv[1]*vv[1] + vv[2]*vv[2] + vv[3]*vv[3];
            #pragma unroll
            for (int m = 4; m <= 32; m <<= 1) {
                s1 += __shfl_xor(s1, m);
                s2 += __shfl_xor(s2, m);
            }
            float mean = s1 * 0.015625f;
            float rstd = rsqrtf(s2 * 0.015625f - mean * mean + 1e-5f);
            float qv[4];
            #pragma unroll
            for (int j = 0; j < 4; j++) {
                x1v[i][j] = (vv[j] - mean) * rstd * gg[j] + eb[j];
                qv[j] = __cosf(x1v[i][j]) * cth;
            }
            qpk[((c0 >> 1) + 0) * 34 + r0 + i] = pkrtz(qv[0], qv[1]);
            qpk[((c0 >> 1) + 1) * 34 + r0 + i] = pkrtz(qv[2], qv[3]);
        }
    }
    __syncthreads();

    float4 w2r[8];
    #pragma unroll
    for (int t = 0; t < 8; t++) w2r[t] = ((const float4*)W2)[tid + t * 512];

    {                                         // GEMM2: all 512 threads
        const int r2 = (tid & 15) * 2;
        const int f0 = (tid >> 4) * 8;
        float acc2[2][8] = {};
        #pragma unroll 4
        for (int kp = 0; kp < 32; kp++) {
            uint2 a = *(const uint2*)&qpk[kp * 34 + r2];
            uint4 b0 = *(const uint4*)&W1p[kp * 260 + f0];
            uint4 b1q = *(const uint4*)&W1p[kp * 260 + f0 + 4];
            unsigned int bb[8] = {b0.x, b0.y, b0.z, b0.w, b1q.x, b1q.y, b1q.z, b1q.w};
            #pragma unroll
            for (int j = 0; j < 8; j++) {
                acc2[0][j] = dot2(a.x, bb[j], acc2[0][j]);
                acc2[1][j] = dot2(a.y, bb[j], acc2[1][j]);
            }
        }
        float4 c1a = *(const float4*)&b1[f0];
        float4 c1b = *(const float4*)&b1[f0 + 4];
        float bb[8] = {c1a.x, c1a.y, c1a.z, c1a.w, c1b.x, c1b.y, c1b.z, c1b.w};
        __syncthreads();                      // qpk/W1p reads done before hrow/W2p writes
        #pragma unroll
        for (int i = 0; i < 2; i++) {
            float hv[8];
            #pragma unroll
            for (int j = 0; j < 8; j++) hv[j] = fmaxf(acc2[i][j] + bb[j], 0.f);
            uint4 hq;
            hq.x = pkrtz(hv[0], hv[1]); hq.y = pkrtz(hv[2], hv[3]);
            hq.z = pkrtz(hv[4], hv[5]); hq.w = pkrtz(hv[6], hv[7]);
            *(uint4*)&hrow[(r2 + i) * 132 + (f0 >> 1)] = hq;
        }
    }

    #pragma unroll
    for (int t = 0; t < 8; t++) {             // W2 regs -> LDS
        int fi = tid + t * 512;
        int e = fi >> 6, k0 = (fi & 63) * 4;
        W2p[(k0 >> 1) * 68 + e] = pkrtz(w2r[t].x, w2r[t].y);
        W2p[((k0 >> 1) + 1) * 68 + e] = pkrtz(w2r[t].z, w2r[t].w);
    }
    __syncthreads();

    if (tid < 256) {                          // GEMM3 + ep3
        float acc3[2][4] = {};
        #pragma unroll 4
        for (int fp0 = 0; fp0 < 128; fp0 += 4) {
            uint4 a0 = *(const uint4*)&hrow[(r0 + 0) * 132 + fp0];
            uint4 a1 = *(const uint4*)&hrow[(r0 + 1) * 132 + fp0];
            uint4 b0 = *(const uint4*)&W2p[(fp0 + 0) * 68 + c0];
            uint4 b1q = *(const uint4*)&W2p[(fp0 + 1) * 68 + c0];
            uint4 b2q = *(const uint4*)&W2p[(fp0 + 2) * 68 + c0];
            uint4 b3q = *(const uint4*)&W2p[(fp0 + 3) * 68 + c0];
            unsigned int aa[2][4] = {{a0.x, a0.y, a0.z, a0.w},
                                     {a1.x, a1.y, a1.z, a1.w}};
            unsigned int bbb[4][4] = {{b0.x, b0.y, b0.z, b0.w},
                                      {b1q.x, b1q.y, b1q.z, b1q.w},
                                      {b2q.x, b2q.y, b2q.z, b2q.w},
                                      {b3q.x, b3q.y, b3q.z, b3q.w}};
            #pragma unroll
            for (int i = 0; i < 2; i++)
                #pragma unroll
                for (int j = 0; j < 4; j++) {
                    float t0 = dot2(aa[i][0], bbb[0][j], acc3[i][j]);
                    t0 = dot2(aa[i][1], bbb[1][j], t0);
                    t0 = dot2(aa[i][2], bbb[2][j], t0);
                    acc3[i][j] = dot2(aa[i][3], bbb[3][j], t0);
                }
        }
        float4 b24 = *(const float4*)&b2[c0];
        float4 g24 = *(const float4*)&g2[c0];
        float4 be24 = *(const float4*)&be2[c0];
        #pragma unroll
        for (int i = 0; i < 2; i++) {
            float vv[4] = {x1v[i][0] + acc3[i][0] + b24.x,
                           x1v[i][1] + acc3[i][1] + b24.y,
                           x1v[i][2] + acc3[i][2] + b24.z,
                           x1v[i][3] + acc3[i][3] + b24.w};
            float s1 = vv[0] + vv[1] + vv[2] + vv[3];
            float s2 = vv[0]*vv[0] + vv[1]*vv[1] + vv[2]*vv[2] + vv[3]*vv[3];
            #pragma unroll
            for (int m = 4; m <= 32; m <<= 1) {
                s1 += __shfl_xor(s1, m);
                s2 += __shfl_xor(s2, m);
            }
            float mean = s1 * 0.015625f;
            float rstd = rsqrtf(s2 * 0.015625f - mean * mean + 1e-5f);
            float4 o;
            o.x = (vv[0] - mean) * rstd * g24.x + be24.x;
            o.y = (vv[1] - mean) * rstd * g24.y + be24.y;
            o.z = (vv[2] - mean) * rstd * g24.z + be24.z;
            o.w = (vv[3] - mean) * rstd * g24.w + be24.w;
            *(float4*)(outp + (size_t)(n0 + r0 + i) * 64 + c0) = o;
        }
    }
}

// ---------------------------------------------------------------------------
extern "C" void kernel_launch(void* const* d_in, const int* in_sizes, int n_in,
                              void* d_out, int out_size, void* d_ws, size_t ws_size,
                              hipStream_t stream)
{
    const float* x   = (const float*)d_in[0];
    const float* Wq  = (const float*)d_in[1];
    const float* bq  = (const float*)d_in[2];
    const float* Wk  = (const float*)d_in[3];
    const float* bk  = (const float*)d_in[4];
    const float* Wv  = (const float*)d_in[5];
    const float* bv  = (const float*)d_in[6];
    const float* Wo  = (const float*)d_in[7];
    const float* bo  = (const float*)d_in[8];
    const float* tha = (const float*)d_in[9];
    const float* thf = (const float*)d_in[10];
    const float* W1  = (const float*)d_in[11];
    const float* b1  = (const float*)d_in[12];
    const float* W2  = (const float*)d_in[13];
    const float* b2  = (const float*)d_in[14];
    const float* g1  = (const float*)d_in[15];
    const float* be1 = (const float*)d_in[16];
    const float* g2  = (const float*)d_in[17];
    const float* be2 = (const float*)d_in[18];

    // workspace: qb(2M) kb(2M) vb(2M) attn(4M)
    char* wsb = (char*)d_ws;
    unsigned short* qbp = (unsigned short*)(wsb);
    unsigned short* kbp = (unsigned short*)(wsb + (2u << 20));
    unsigned short* vbp = (unsigned short*)(wsb + (4u << 20));
    float* attn = (float*)(wsb + (6u << 20));

    qkv_kernel<<<256, 512, 0, stream>>>(x, Wq, bq, Wk, bk, Wv, bv, tha, qbp, kbp, vbp);
    attn_kernel<<<1024, 256, 0, stream>>>(qbp, kbp, vbp, attn);
    tail_kernel<<<512, 512, 0, stream>>>(attn, x, Wo, bo, g1, be1, thf,
                                         W1, b1, W2, b2, g2, be2, (float*)d_out);
}

// Round 8
// 136.821 us; speedup vs baseline: 1.7003x; 1.0870x over previous
//
#include <hip/hip_runtime.h>
#include <hip/hip_bf16.h>

#define B_ 8
#define T_ 2048
#define NROWS 16384

typedef __attribute__((ext_vector_type(16))) float f32x16;
typedef __attribute__((ext_vector_type(8))) short short8;
typedef __fp16 half2_t __attribute__((ext_vector_type(2)));
typedef __fp16 half8_t __attribute__((ext_vector_type(8)));

__device__ __forceinline__ unsigned int pkrtz(float a, float b) {
    half2_t h = __builtin_amdgcn_cvt_pkrtz(a, b);
    return __builtin_bit_cast(unsigned int, h);
}
// pack two fp32 into one dword of bf16 (truncate): low short = a, high = b
__device__ __forceinline__ unsigned int pkbf(float a, float b) {
    return __builtin_amdgcn_perm(__float_as_uint(b), __float_as_uint(a), 0x07060302u);
}
__device__ __forceinline__ float dot2(unsigned int a, unsigned int b, float c) {
    return __builtin_amdgcn_fdot2(__builtin_bit_cast(half2_t, a),
                                  __builtin_bit_cast(half2_t, b), c, false);
}
__device__ __forceinline__ float fast_exp2(float x) {
#if __has_builtin(__builtin_amdgcn_exp2f)
    return __builtin_amdgcn_exp2f(x);
#else
    return exp2f(x);
#endif
}

// ---------------------------------------------------------------------------
// Kernel 1: QKV projection (dot2) + cos(.+theta) + bf16 pack to [B,H,T,DK].
// (unchanged from round 7)
// ---------------------------------------------------------------------------
__global__ __launch_bounds__(512, 2) void qkv_kernel(
    const float* __restrict__ x,
    const float* __restrict__ Wq, const float* __restrict__ bq,
    const float* __restrict__ Wk, const float* __restrict__ bk,
    const float* __restrict__ Wv, const float* __restrict__ bv,
    const float* __restrict__ theta_attn,
    unsigned short* __restrict__ qb, unsigned short* __restrict__ kbuf,
    unsigned short* __restrict__ vbuf)
{
    __shared__ unsigned int xpk[32 * 66];
    __shared__ unsigned int wpk[32 * 196];
    __shared__ unsigned int outs[6144];
    const int tid = threadIdx.x;
    const int n0 = blockIdx.x * 64;

    #pragma unroll
    for (int t = 0; t < 2; t++) {
        int fi = tid + t * 512;
        float4 v = ((const float4*)(x + (size_t)n0 * 64))[fi];
        int r = fi >> 4, k0 = (fi & 15) * 4;
        xpk[(k0 >> 1) * 66 + r] = pkrtz(v.x, v.y);
        xpk[((k0 >> 1) + 1) * 66 + r] = pkrtz(v.z, v.w);
    }
    const float* Wm[3] = {Wq, Wk, Wv};
    #pragma unroll
    for (int t = 0; t < 6; t++) {
        int fi = tid + t * 512;
        int m = fi >> 10, j = (fi >> 4) & 63, k0 = (fi & 15) * 4;
        float4 v = ((const float4*)Wm[m])[fi & 1023];
        wpk[(k0 >> 1) * 196 + m * 64 + j] = pkrtz(v.x, v.y);
        wpk[((k0 >> 1) + 1) * 196 + m * 64 + j] = pkrtz(v.z, v.w);
    }
    __syncthreads();

    const int r0 = (tid & 31) * 2;
    const int c0 = (tid >> 5) * 12;
    float acc[2][12] = {};
    #pragma unroll 8
    for (int kp = 0; kp < 32; kp++) {
        uint2 a = *(const uint2*)&xpk[kp * 66 + r0];
        uint4 b0 = *(const uint4*)&wpk[kp * 196 + c0];
        uint4 b1 = *(const uint4*)&wpk[kp * 196 + c0 + 4];
        uint4 b2 = *(const uint4*)&wpk[kp * 196 + c0 + 8];
        unsigned int bb[12] = {b0.x, b0.y, b0.z, b0.w,
                               b1.x, b1.y, b1.z, b1.w,
                               b2.x, b2.y, b2.z, b2.w};
        #pragma unroll
        for (int j = 0; j < 12; j++) {
            acc[0][j] = dot2(a.x, bb[j], acc[0][j]);
            acc[1][j] = dot2(a.y, bb[j], acc[1][j]);
        }
    }

    {
        const float th = *theta_attn;
        const float QS = 0.51006980f;
        const float* biasp[3] = {bq, bk, bv};
        float bcol[12];
        #pragma unroll
        for (int j = 0; j < 12; j++) {
            int c = c0 + j;
            bcol[j] = biasp[c >> 6][c & 63];
        }
        #pragma unroll
        for (int i = 0; i < 2; i++) {
            float vals[12];
            #pragma unroll
            for (int j = 0; j < 12; j++) {
                float v = __cosf(acc[i][j] + bcol[j] + th);
                vals[j] = ((c0 + j) >> 6) == 0 ? v * QS : v;
            }
            int row = r0 + i;
            #pragma unroll
            for (int t = 0; t < 6; t++) {
                int c = c0 + 2 * t;
                outs[(c >> 3) * 256 + row * 4 + ((c & 7) >> 1)] = pkbf(vals[2*t], vals[2*t+1]);
            }
        }
    }
    __syncthreads();

    unsigned short* outp3[3] = {qb, kbuf, vbuf};
    #pragma unroll
    for (int t = 0; t < 3; t++) {
        int fi = tid + t * 512;
        int bh = fi >> 6, r2 = fi & 63;
        int m = bh >> 3, hI = bh & 7;
        uint4 v = *(const uint4*)&outs[4 * fi];
        int n = n0 + r2;
        unsigned short* dst = outp3[m] +
            ((size_t)((n >> 11) * 8 + hI) * 2048 + (n & 2047)) * 8;
        *(uint4*)dst = v;
    }
}

// ---------------------------------------------------------------------------
// Kernel 2: flash attention (unchanged from round 7).
// ---------------------------------------------------------------------------
__global__ __launch_bounds__(256, 4) void attn_kernel(
    const unsigned short* __restrict__ qb,
    const unsigned short* __restrict__ kbuf,
    const unsigned short* __restrict__ vbuf,
    float* __restrict__ attn)
{
    __shared__ __align__(16) unsigned short Ks[1024 * 8];
    __shared__ __align__(16) unsigned short Vt[9 * 1032];
    const int tid = threadIdx.x;
    const int head = blockIdx.x >> 4;
    const int qblk = blockIdx.x & 15;
    const size_t hoff = (size_t)head * T_ * 8;
    const int wave = tid >> 6, lane = tid & 63;
    const int col = lane & 31, h = lane >> 5;
    const int q0 = qblk * 128 + wave * 32;

    const short8 z8 = {0, 0, 0, 0, 0, 0, 0, 0};
    short8 bqf = z8;
    if (h == 0) bqf = *(const short8*)(qb + hoff + (size_t)(q0 + col) * 8);

    if (tid < 128)
        ((uint4*)(Vt + 8 * 1032))[tid] =
            make_uint4(0x3f803f80u, 0x3f803f80u, 0x3f803f80u, 0x3f803f80u);

    f32x16 oacc = {0.f,0.f,0.f,0.f,0.f,0.f,0.f,0.f,0.f,0.f,0.f,0.f,0.f,0.f,0.f,0.f};
    const f32x16 z16 = {0.f,0.f,0.f,0.f,0.f,0.f,0.f,0.f,0.f,0.f,0.f,0.f,0.f,0.f,0.f,0.f};
    const unsigned short* vbase = &Vt[(col < 9 ? col : 8) * 1032 + 8 * h];
    short8 ak = z8;

    for (int half = 0; half < 2; half++) {
        __syncthreads();
        {
            const uint4* kg = (const uint4*)(kbuf + hoff + (size_t)half * 1024 * 8);
            const uint4* vg = (const uint4*)(vbuf + hoff + (size_t)half * 1024 * 8);
            #pragma unroll
            for (int it = 0; it < 4; it++) {
                int s = tid + it * 256;
                ((uint4*)Ks)[s] = kg[s];
                union { uint4 u; unsigned short us[8]; } cv;
                cv.u = vg[s];
                int sp = (s & ~12) | ((s & 4) << 1) | ((s & 8) >> 1);
                #pragma unroll
                for (int d = 0; d < 8; d++) Vt[d * 1032 + sp] = cv.us[d];
            }
        }
        __syncthreads();

        for (int s0 = 0; s0 < 1024; s0 += 32) {
            if (h == 0) ak = *(const short8*)&Ks[(s0 + col) * 8];
            f32x16 S = __builtin_amdgcn_mfma_f32_32x32x16_bf16(ak, bqf, z16, 0, 0, 0);
            #pragma unroll
            for (int g = 0; g < 2; g++) {
                const int o = g * 8;
                union { unsigned int u[4]; short8 s; } bp;
                bp.u[0] = pkbf(fast_exp2(S[o+0]), fast_exp2(S[o+1]));
                bp.u[1] = pkbf(fast_exp2(S[o+2]), fast_exp2(S[o+3]));
                bp.u[2] = pkbf(fast_exp2(S[o+4]), fast_exp2(S[o+5]));
                bp.u[3] = pkbf(fast_exp2(S[o+6]), fast_exp2(S[o+7]));
                short8 av = *(const short8*)&vbase[s0 + g * 16];
                oacc = __builtin_amdgcn_mfma_f32_32x32x16_bf16(av, bp.s, oacc, 0, 0, 0);
            }
        }
    }

    float tot = oacc[4];
    tot += __shfl_xor(tot, 32);
    const float inv = 1.0f / tot;
    const int bI = head >> 3, hI = head & 7;
    const int q = q0 + col;
    #pragma unroll
    for (int rr = 0; rr < 4; rr++) {
        int d = 4 * h + rr;
        attn[((size_t)bI * 2048 + q) * 64 + hI * 8 + d] = oacc[rr] * inv;
    }
}

// ---------------------------------------------------------------------------
// Kernel 3 (fused tail, MFMA-based): y=At@Wo^T+bo; x1=LN(x+y);
// qout=cos(x1)cos(thf); h=relu(qout@W1^T+b1); f=h@W2^T+b2; out=LN(x1+f).
// All GEMMs use f16 32x32x16 MFMA (same fp16 quantization as the previous
// dot2 path). Operands staged ROW-MAJOR fp16-pairs (global layouts already
// [n][k] -- zero transposes). Verified layouts: A: m=lane&31,k=8h+j;
// B: n=lane&31,k=8h+j; C: col=lane&31,row=(reg&3)+8*(reg>>2)+4h.
// G1/G3 run on 2 waves (8/32 MFMA); G2 on all 8 (one 32-f tile each).
// Epilogues on a 512-thread 1row x 4col mapping; x1 stays in registers.
// ---------------------------------------------------------------------------
__global__ __launch_bounds__(512, 4) void tail_kernel(
    const float* __restrict__ attn, const float* __restrict__ x,
    const float* __restrict__ Wo, const float* __restrict__ bo,
    const float* __restrict__ g1, const float* __restrict__ be1,
    const float* __restrict__ theta_ffn,
    const float* __restrict__ W1, const float* __restrict__ b1,
    const float* __restrict__ W2, const float* __restrict__ b2,
    const float* __restrict__ g2, const float* __restrict__ be2,
    float* __restrict__ outp)
{
    // region map (dwords), phase-aliased:
    //  W1p [0,9216) [256f][36] -> W2p [0,8448) [64e][132] after G2
    //  Atp [9216,10368) [32r][36] -> qoutp (same) after G1
    //  Wop [10368,12672) [64n][36] -> hrowp [10368,14592) [32r][132] after ep1
    //  Yf  [12672,14848) fp32 [32][68] (G1 C; dead after ep1, aliased by hrowp)
    //  Y2a [14592,15744) fp32 [32][36] cols 0-31 ; Y2b [8448,9600) cols 32-63
    __shared__ unsigned int smem[15744];
    const int tid = threadIdx.x;
    const int lane = tid & 63;
    const int wave = tid >> 6;
    const int h = lane >> 5;
    const int n0 = blockIdx.x * 32;
    const int mrow = tid >> 4;             // epilogue row 0..31
    const int c0 = (tid & 15) * 4;         // epilogue cols

    unsigned int* const W1p = smem;
    unsigned int* const W2p = smem;
    unsigned int* const Atp = smem + 9216;
    unsigned int* const qoutp = smem + 9216;
    unsigned int* const Wop = smem + 10368;
    unsigned int* const hrowp = smem + 10368;
    float* const Yf = (float*)(smem + 12672);
    float* const Y2a = (float*)(smem + 14592);
    float* const Y2b = (float*)(smem + 8448);

    const f32x16 z16 = {0.f,0.f,0.f,0.f,0.f,0.f,0.f,0.f,0.f,0.f,0.f,0.f,0.f,0.f,0.f,0.f};

    // ---- early global issues ----
    float4 atv = ((const float4*)(attn + (size_t)n0 * 64))[tid];
    float4 wo0 = ((const float4*)Wo)[tid];
    float4 wo1 = ((const float4*)Wo)[tid + 512];
    float4 xv = *(const float4*)(x + (size_t)(n0 + mrow) * 64 + c0);
    float4 w1r[8];
    #pragma unroll
    for (int t = 0; t < 8; t++) w1r[t] = ((const float4*)W1)[tid + t * 512];

    // ---- stage At [32][36] + Wo [64][36] row-major fp16 pairs ----
    {
        int r = tid >> 4, k0 = (tid & 15) * 4;
        uint2 a2 = make_uint2(pkrtz(atv.x, atv.y), pkrtz(atv.z, atv.w));
        *(uint2*)&Atp[r * 36 + (k0 >> 1)] = a2;
        uint2 wa = make_uint2(pkrtz(wo0.x, wo0.y), pkrtz(wo0.z, wo0.w));
        *(uint2*)&Wop[r * 36 + (k0 >> 1)] = wa;
        int fi = tid + 512;
        int e1 = fi >> 4, k1 = (fi & 15) * 4;
        uint2 wb = make_uint2(pkrtz(wo1.x, wo1.y), pkrtz(wo1.z, wo1.w));
        *(uint2*)&Wop[e1 * 36 + (k1 >> 1)] = wb;
    }
    __syncthreads();                        // B1: At, Wo ready

    // ---- W1 regs -> W1p [256][36] (all threads) ----
    #pragma unroll
    for (int t = 0; t < 8; t++) {
        int fi = tid + t * 512;
        int f = fi >> 4, k0 = (fi & 15) * 4;
        uint2 w2 = make_uint2(pkrtz(w1r[t].x, w1r[t].y), pkrtz(w1r[t].z, w1r[t].w));
        *(uint2*)&W1p[f * 36 + (k0 >> 1)] = w2;
    }

    // ---- G1: y = At @ Wo^T + bo  (waves 0-1, one 32-col tile each) ----
    if (wave < 2) {
        const int colo = wave * 32 + (lane & 31);
        f32x16 acc = z16;
        #pragma unroll
        for (int kk = 0; kk < 4; kk++) {
            half8_t a = __builtin_bit_cast(half8_t,
                *(const uint4*)&Atp[(lane & 31) * 36 + kk * 8 + h * 4]);
            half8_t b = __builtin_bit_cast(half8_t,
                *(const uint4*)&Wop[colo * 36 + kk * 8 + h * 4]);
            acc = __builtin_amdgcn_mfma_f32_32x32x16_f16(a, b, acc, 0, 0, 0);
        }
        float bov = bo[colo];
        #pragma unroll
        for (int reg = 0; reg < 16; reg++) {
            int rr = (reg & 3) + 8 * (reg >> 2) + 4 * h;
            Yf[rr * 68 + colo] = acc[reg] + bov;
        }
    }
    __syncthreads();                        // B2: Y + W1p ready

    // ---- ep1: x1 = LN(x+y) (regs); qout = cos(x1)*cos(thf) -> qoutp ----
    float x1v[4];
    {
        float4 yv = *(const float4*)&Yf[mrow * 68 + c0];
        float vv[4] = {xv.x + yv.x, xv.y + yv.y, xv.z + yv.z, xv.w + yv.w};
        float s1 = vv[0] + vv[1] + vv[2] + vv[3];
        float s2 = vv[0]*vv[0] + vv[1]*vv[1] + vv[2]*vv[2] + vv[3]*vv[3];
        #pragma unroll
        for (int m = 1; m <= 8; m <<= 1) {
            s1 += __shfl_xor(s1, m);
            s2 += __shfl_xor(s2, m);
        }
        float mean = s1 * 0.015625f;
        float rstd = rsqrtf(s2 * 0.015625f - mean * mean + 1e-5f);
        float4 g14 = *(const float4*)&g1[c0];
        float4 be14 = *(const float4*)&be1[c0];
        float gg[4] = {g14.x, g14.y, g14.z, g14.w};
        float eb[4] = {be14.x, be14.y, be14.z, be14.w};
        float cth = __cosf(*theta_ffn);
        float qv[4];
        #pragma unroll
        for (int j = 0; j < 4; j++) {
            x1v[j] = (vv[j] - mean) * rstd * gg[j] + eb[j];
            qv[j] = __cosf(x1v[j]) * cth;
        }
        uint2 q2 = make_uint2(pkrtz(qv[0], qv[1]), pkrtz(qv[2], qv[3]));
        *(uint2*)&qoutp[mrow * 36 + (c0 >> 1)] = q2;
    }
    __syncthreads();                        // B3: qout ready

    // ---- W2 prefetch (in flight across G2) ----
    float4 w2r[8];
    #pragma unroll
    for (int t = 0; t < 8; t++) w2r[t] = ((const float4*)W2)[tid + t * 512];

    // ---- G2: h^T = W1 @ qout^T (C^T form), relu+bias, -> hrowp row-major ----
    {
        const int fl = lane & 31;
        f32x16 acc = z16;
        #pragma unroll
        for (int kk = 0; kk < 4; kk++) {
            half8_t a = __builtin_bit_cast(half8_t,
                *(const uint4*)&W1p[(wave * 32 + fl) * 36 + kk * 8 + h * 4]);
            half8_t b = __builtin_bit_cast(half8_t,
                *(const uint4*)&qoutp[fl * 36 + kk * 8 + h * 4]);
            acc = __builtin_amdgcn_mfma_f32_32x32x16_f16(a, b, acc, 0, 0, 0);
        }
        const int row = lane & 31;          // x-row = C col
        #pragma unroll
        for (int q = 0; q < 4; q++) {       // regs 4q..4q+3 = f 8q+4h+0..3 (+32*wave)
            int fb = wave * 32 + 8 * q + 4 * h;
            float4 b1v = *(const float4*)&b1[fb];
            float h0 = fmaxf(acc[4*q+0] + b1v.x, 0.f);
            float h1 = fmaxf(acc[4*q+1] + b1v.y, 0.f);
            float h2 = fmaxf(acc[4*q+2] + b1v.z, 0.f);
            float h3 = fmaxf(acc[4*q+3] + b1v.w, 0.f);
            uint2 hp = make_uint2(pkrtz(h0, h1), pkrtz(h2, h3));
            *(uint2*)&hrowp[row * 132 + (fb >> 1)] = hp;
        }
    }
    __syncthreads();                        // B4: hrow ready, W1 dead

    // ---- W2 regs -> W2p [64][132] row-major ----
    #pragma unroll
    for (int t = 0; t < 8; t++) {
        int fi = tid + t * 512;
        int e = fi >> 6, k0 = (fi & 63) * 4;
        uint2 w2 = make_uint2(pkrtz(w2r[t].x, w2r[t].y), pkrtz(w2r[t].z, w2r[t].w));
        *(uint2*)&W2p[e * 132 + (k0 >> 1)] = w2;
    }
    __syncthreads();                        // B5: W2p ready

    // ---- G3: f = h @ W2^T + b2  (waves 0-1, one 32-col tile each) ----
    if (wave < 2) {
        const int colo = wave * 32 + (lane & 31);
        f32x16 acc = z16;
        #pragma unroll
        for (int kk = 0; kk < 16; kk++) {
            half8_t a = __builtin_bit_cast(half8_t,
                *(const uint4*)&hrowp[(lane & 31) * 132 + kk * 8 + h * 4]);
            half8_t b = __builtin_bit_cast(half8_t,
                *(const uint4*)&W2p[colo * 132 + kk * 8 + h * 4]);
            acc = __builtin_amdgcn_mfma_f32_32x32x16_f16(a, b, acc, 0, 0, 0);
        }
        float b2v = b2[colo];
        float* Ydst = wave ? Y2b : Y2a;
        const int cl = lane & 31;
        #pragma unroll
        for (int reg = 0; reg < 16; reg++) {
            int rr = (reg & 3) + 8 * (reg >> 2) + 4 * h;
            Ydst[rr * 36 + cl] = acc[reg] + b2v;
        }
    }
    __syncthreads();                        // B6: Y2 ready

    // ---- ep3: out = LN(x1 + f) * g2 + be2 ----
    {
        float4 fv = (c0 < 32) ? *(const float4*)&Y2a[mrow * 36 + c0]
                              : *(const float4*)&Y2b[mrow * 36 + (c0 - 32)];
        float vv[4] = {x1v[0] + fv.x, x1v[1] + fv.y, x1v[2] + fv.z, x1v[3] + fv.w};
        float s1 = vv[0] + vv[1] + vv[2] + vv[3];
        float s2 = vv[0]*vv[0] + vv[1]*vv[1] + vv[2]*vv[2] + vv[3]*vv[3];
        #pragma unroll
        for (int m = 1; m <= 8; m <<= 1) {
            s1 += __shfl_xor(s1, m);
            s2 += __shfl_xor(s2, m);
        }
        float mean = s1 * 0.015625f;
        float rstd = rsqrtf(s2 * 0.015625f - mean * mean + 1e-5f);
        float4 g24 = *(const float4*)&g2[c0];
        float4 be24 = *(const float4*)&be2[c0];
        float4 o;
        o.x = (vv[0] - mean) * rstd * g24.x + be24.x;
        o.y = (vv[1] - mean) * rstd * g24.y + be24.y;
        o.z = (vv[2] - mean) * rstd * g24.z + be24.z;
        o.w = (vv[3] - mean) * rstd * g24.w + be24.w;
        *(float4*)(outp + (size_t)(n0 + mrow) * 64 + c0) = o;
    }
}

// ---------------------------------------------------------------------------
extern "C" void kernel_launch(void* const* d_in, const int* in_sizes, int n_in,
                              void* d_out, int out_size, void* d_ws, size_t ws_size,
                              hipStream_t stream)
{
    const float* x   = (const float*)d_in[0];
    const float* Wq  = (const float*)d_in[1];
    const float* bq  = (const float*)d_in[2];
    const float* Wk  = (const float*)d_in[3];
    const float* bk  = (const float*)d_in[4];
    const float* Wv  = (const float*)d_in[5];
    const float* bv  = (const float*)d_in[6];
    const float* Wo  = (const float*)d_in[7];
    const float* bo  = (const float*)d_in[8];
    const float* tha = (const float*)d_in[9];
    const float* thf = (const float*)d_in[10];
    const float* W1  = (const float*)d_in[11];
    const float* b1  = (const float*)d_in[12];
    const float* W2  = (const float*)d_in[13];
    const float* b2  = (const float*)d_in[14];
    const float* g1  = (const float*)d_in[15];
    const float* be1 = (const float*)d_in[16];
    const float* g2  = (const float*)d_in[17];
    const float* be2 = (const float*)d_in[18];

    // workspace: qb(2M) kb(2M) vb(2M) attn(4M)
    char* wsb = (char*)d_ws;
    unsigned short* qbp = (unsigned short*)(wsb);
    unsigned short* kbp = (unsigned short*)(wsb + (2u << 20));
    unsigned short* vbp = (unsigned short*)(wsb + (4u << 20));
    float* attn = (float*)(wsb + (6u << 20));

    qkv_kernel<<<256, 512, 0, stream>>>(x, Wq, bq, Wk, bk, Wv, bv, tha, qbp, kbp, vbp);
    attn_kernel<<<1024, 256, 0, stream>>>(qbp, kbp, vbp, attn);
    tail_kernel<<<512, 512, 0, stream>>>(attn, x, Wo, bo, g1, be1, thf,
                                         W1, b1, W2, b2, g2, be2, (float*)d_out);
}